// Round 7
// baseline (184.431 us; speedup 1.0000x reference)
//
#include <hip/hip_runtime.h>
#include <stdint.h>

#define TT 64
#define BB 128
#define VV 4880
#define NF4R 1220u                   // float4 per row
#define NROWS (TT * BB)              // 8192
#define TOTF4 9994240u               // NROWS * NF4R
#define HOFF  4997181u               // TOTF4/2 + 61: breaks power-of-2 set aliasing
#define NTH   (2048u * 256u)         // phase-1 total threads
#define LOG_EPS_F 1e-8f
#define NBUCKET 64
#define NQ 9
#define THR0 0.992f                  // ~39 candidates/row (band 20..64)
#define CAPR 64                      // per-row candidate capacity
#define PPCAP 96                     // per-row positive-position capacity (~49+6sigma)
#define LDSC 768                     // per-block candidate staging
#define PLC  384                     // per-block positive staging (~195 avg)

// full u64 key for rescan path: (value desc, idx asc) via single compare
__device__ __forceinline__ uint64_t mkkey64(float v, int idx) {
  return ((uint64_t)__float_as_uint(v) << 13) | (uint64_t)(8191 - idx);
}
// compact u32 key (values > THR0 only); same ordering as mkkey64 on that range
__device__ __forceinline__ uint32_t mkkey32(float v, uint32_t idx) {
  return ((__float_as_uint(v) - __float_as_uint(THR0)) << 13) | (8191u - idx);
}

__device__ __forceinline__ int lane_prefix(unsigned long long m) {
  return __builtin_amdgcn_mbcnt_hi((unsigned)(m >> 32),
         __builtin_amdgcn_mbcnt_lo((unsigned)m, 0));
}

// ---------------- phase 1: decoupled-stream scan ----------------
__global__ __launch_bounds__(256) void stream_kernel(
    const float* __restrict__ yhat, const float* __restrict__ yy,
    const float* __restrict__ length, float* __restrict__ bucket,
    uint32_t* __restrict__ cnt, uint32_t* __restrict__ ppos,
    uint32_t* __restrict__ cand, uint16_t* __restrict__ pidx) {
  __shared__ float invlen_sh[BB];
  __shared__ uint64_t lbuf[LDSC];
  __shared__ uint32_t plbuf[PLC];
  __shared__ int blkc, blkp;

  const int t = threadIdx.x;
  if (t < BB) invlen_sh[t] = 1.0f / length[t];
  if (t == 0) { blkc = 0; blkp = 0; }
  __syncthreads();

  const unsigned gtid = blockIdx.x * 256u + t;
  const float4* h4 = (const float4*)yhat;
  const float4* y4 = (const float4*)yy;

  float ls = 0.0f;    // sum over yhat of log(1-yh+eps) * invlen(row)
  float np = 0.0f;    // sum of y

  auto proc_h = [&](float4 h, unsigned i) {
    unsigned row = (unsigned)(((uint64_t)i * 112654880ull) >> 37);  // i/1220 exact
    float il = invlen_sh[row & (BB - 1)];
    float a0 = 1.0f - h.x + LOG_EPS_F, a1 = 1.0f - h.y + LOG_EPS_F;
    float a2 = 1.0f - h.z + LOG_EPS_F, a3 = 1.0f - h.w + LOG_EPS_F;
    ls = fmaf(__logf((a0 * a1) * (a2 * a3)), il, ls);   // prod >= ~1e-16
    float hm = fmaxf(fmaxf(h.x, h.y), fmaxf(h.z, h.w));
    if (hm > THR0) {                                    // ~3% of float4s
      unsigned base = (i - row * NF4R) * 4u;
      const float hv[4] = {h.x, h.y, h.z, h.w};
      #pragma unroll
      for (int e = 0; e < 4; ++e) {
        if (hv[e] > THR0) {
          uint32_t key = mkkey32(hv[e], base + e);
          int s = atomicAdd(&blkc, 1);
          if (s < LDSC) lbuf[s] = ((uint64_t)row << 32) | key;
          else { uint32_t sl = atomicAdd(&cnt[row], 1u);
                 if (sl < CAPR) cand[row * CAPR + sl] = key; }
        }
      }
    }
  };
  auto proc_y = [&](float4 v, unsigned j) {
    np += (v.x + v.y) + (v.z + v.w);                    // y is exactly 0/1
    if (v.x != 0.f || v.y != 0.f || v.z != 0.f || v.w != 0.f) {  // ~4% of float4s
      unsigned row = (unsigned)(((uint64_t)j * 112654880ull) >> 37);
      unsigned base = (j - row * NF4R) * 4u;
      const float yv[4] = {v.x, v.y, v.z, v.w};
      #pragma unroll
      for (int e = 0; e < 4; ++e) {
        if (yv[e] != 0.f) {
          uint32_t pk = (row << 13) | (base + e);       // 13b row | 13b idx
          int s = atomicAdd(&blkp, 1);
          if (s < PLC) plbuf[s] = pk;
          else { uint32_t sl = atomicAdd(&ppos[row], 1u);
                 if (sl < PPCAP) pidx[row * PPCAP + sl] = (uint16_t)(base + e); }
        }
      }
    }
  };

  unsigned i = gtid;
  for (; i + NTH < TOTF4; i += 2u * NTH) {
    unsigned i2 = i + NTH;
    unsigned j  = i  + HOFF; if (j  >= TOTF4) j  -= TOTF4;
    unsigned j2 = i2 + HOFF; if (j2 >= TOTF4) j2 -= TOTF4;
    float4 ha = h4[i],  va = y4[j];
    float4 hb = h4[i2], vb = y4[j2];
    proc_h(ha, i);  proc_y(va, j);
    proc_h(hb, i2); proc_y(vb, j2);
  }
  if (i < TOTF4) {
    unsigned j = i + HOFF; if (j >= TOTF4) j -= TOTF4;
    proc_h(h4[i], i); proc_y(y4[j], j);
  }

  #pragma unroll
  for (int sh = 32; sh >= 1; sh >>= 1) {
    ls += __shfl_xor(ls, sh, 64);
    np += __shfl_xor(np, sh, 64);
  }
  if ((t & 63) == 0) {
    float* bk = bucket + (size_t)((gtid >> 6) & (NBUCKET - 1)) * NQ;
    atomicAdd(bk + 0, -ls * (1.0f / (float)BB));   // cost: -S1 part
    atomicAdd(bk + 5, np);
    atomicAdd(bk + 6, np);
    atomicAdd(bk + 7, np);
    atomicAdd(bk + 8, np);
  }

  __syncthreads();
  const int n = (blkc < LDSC) ? blkc : LDSC;
  for (int k = t; k < n; k += 256) {
    uint64_t u = lbuf[k];
    uint32_t row = (uint32_t)(u >> 32), key = (uint32_t)u;
    uint32_t sl = atomicAdd(&cnt[row], 1u);
    if (sl < CAPR) cand[row * CAPR + sl] = key;
  }
  const int m = (blkp < PLC) ? blkp : PLC;
  for (int k = t; k < m; k += 256) {
    uint32_t pk = plbuf[k];
    uint32_t row = pk >> 13, idx = pk & 8191u;
    uint32_t sl = atomicAdd(&ppos[row], 1u);
    if (sl < PPCAP) pidx[row * PPCAP + sl] = (uint16_t)idx;
  }
}

// ---------------- phase 2: per-row merge + ranking ----------------
__global__ __launch_bounds__(64) void rank_kernel(
    const float* __restrict__ yhat, const float* __restrict__ yy,
    const float* __restrict__ length, float* __restrict__ bucket,
    const uint32_t* __restrict__ cnt, const uint32_t* __restrict__ ppos,
    const uint32_t* __restrict__ cand, const uint16_t* __restrict__ pidx) {
  __shared__ int fbuf[64];
  const int row  = blockIdx.x;
  const int lane = threadIdx.x;
  const uint32_t c  = cnt[row];
  const uint32_t pp = ppos[row];
  const float il = 1.0f / length[row & (BB - 1)];

  float corr = 0.f;                  // sum over positives: log(yh+e)-log(1-yh+e)
  float tpk[4] = {0.f, 0.f, 0.f, 0.f};

  if (c >= 20 && c <= CAPR && pp <= PPCAP) {
    uint32_t k0 = (lane < (int)c) ? cand[row * CAPR + lane] : 0u;
    #pragma unroll
    for (int batch = 0; batch < 2; ++batch) {           // pp <= 96 -> 2 batches
      int p = lane + batch * 64;
      bool act = p < (int)pp;
      int idx = act ? (int)pidx[row * PPCAP + p] : 0;
      float yh = act ? yhat[(size_t)row * VV + idx] : 0.5f;
      if (act) corr += __logf(yh + LOG_EPS_F) - __logf(1.f - yh + LOG_EPS_F);
      bool hi = act && (yh > THR0);                     // candidate-positive
      unsigned long long bal = __ballot(hi);
      while (bal) {                                     // ~0.4 iters/row avg
        int s = __builtin_ctzll(bal);
        bal &= bal - 1;
        int   bidx = __shfl(idx, s, 64);
        float byh  = __shfl(yh, s, 64);
        uint32_t pk = mkkey32(byh, (uint32_t)bidx);
        int cc = (k0 > pk) ? 1 : 0;
        #pragma unroll
        for (int sh = 32; sh >= 1; sh >>= 1) cc += __shfl_xor(cc, sh, 64);
        tpk[0] += (cc < 5);  tpk[1] += (cc < 10);
        tpk[2] += (cc < 15); tpk[3] += (cc < 20);
      }
    }
  } else {
    // ---- rescan path (expected ~10 rows/run) ----
    const float4* hr = (const float4*)(yhat + (size_t)row * VV);
    const float4* yr = (const float4*)(yy   + (size_t)row * VV);
    float thr = THR0;
    auto scan = [&](float th) {
      int c2 = 0;
      for (int f = lane; f < (int)NF4R; f += 64) {
        float4 h = hr[f];
        float hm = fmaxf(fmaxf(h.x, h.y), fmaxf(h.z, h.w));
        bool take = hm > th;
        unsigned long long m = __ballot(take);
        if (m) {
          if (take) { int s = c2 + lane_prefix(m); if (s < 64) fbuf[s] = f; }
          c2 += __popcll(m);
        }
      }
      return c2;
    };
    int lc = scan(thr);
    int attempt = 0;
    while ((lc < 20 || lc > 64) && attempt < 10) {
      thr = (lc < 20) ? 1.0f - (1.0f - thr) * 2.5f
                      : 1.0f - (1.0f - thr) * 0.4f;
      lc = scan(thr);
      ++attempt;
    }
    const int tl = (lc < 64) ? lc : 64;
    const bool act = (lane < tl);
    const int f = act ? fbuf[lane] : 0;
    float4 h = hr[f], v = yr[f];
    uint64_t K0 = mkkey64(h.x, 4 * f),     K1 = mkkey64(h.y, 4 * f + 1);
    uint64_t K2 = mkkey64(h.z, 4 * f + 2), K3 = mkkey64(h.w, 4 * f + 3);
    const bool ve0 = act && (h.x > thr), ve1 = act && (h.y > thr);
    const bool ve2 = act && (h.z > thr), ve3 = act && (h.w > thr);
    int pmask = (ve0 && v.x != 0.0f) ? 1 : 0;
    pmask |= (ve1 && v.y != 0.0f) ? 2 : 0;
    pmask |= (ve2 && v.z != 0.0f) ? 4 : 0;
    pmask |= (ve3 && v.w != 0.0f) ? 8 : 0;
    unsigned long long pl = __ballot(pmask != 0);
    while (pl) {
      int s = __builtin_ctzll(pl);
      pl &= pl - 1;
      int flags = __shfl(pmask, s, 64);
      uint64_t pk0 = __shfl((unsigned long long)K0, s, 64);
      uint64_t pk1 = __shfl((unsigned long long)K1, s, 64);
      uint64_t pk2 = __shfl((unsigned long long)K2, s, 64);
      uint64_t pk3 = __shfl((unsigned long long)K3, s, 64);
      #pragma unroll
      for (int e = 0; e < 4; ++e) {
        if (flags & (1 << e)) {
          uint64_t pk = (e == 0) ? pk0 : (e == 1) ? pk1 : (e == 2) ? pk2 : pk3;
          int cc = (ve0 && K0 > pk) + (ve1 && K1 > pk) +
                   (ve2 && K2 > pk) + (ve3 && K3 > pk);
          #pragma unroll
          for (int sh = 32; sh >= 1; sh >>= 1) cc += __shfl_xor(cc, sh, 64);
          tpk[0] += (cc < 5);  tpk[1] += (cc < 10);
          tpk[2] += (cc < 15); tpk[3] += (cc < 20);
        }
      }
    }
    // correction: scan full y row for ALL positives
    for (int ff = lane; ff < (int)NF4R; ff += 64) {
      float4 vv = yr[ff];
      if (vv.x != 0.f || vv.y != 0.f || vv.z != 0.f || vv.w != 0.f) {
        float4 hh = hr[ff];
        if (vv.x != 0.f) corr += __logf(hh.x + LOG_EPS_F) - __logf(1.f - hh.x + LOG_EPS_F);
        if (vv.y != 0.f) corr += __logf(hh.y + LOG_EPS_F) - __logf(1.f - hh.y + LOG_EPS_F);
        if (vv.z != 0.f) corr += __logf(hh.z + LOG_EPS_F) - __logf(1.f - hh.z + LOG_EPS_F);
        if (vv.w != 0.f) corr += __logf(hh.w + LOG_EPS_F) - __logf(1.f - hh.w + LOG_EPS_F);
      }
    }
  }

  #pragma unroll
  for (int sh = 32; sh >= 1; sh >>= 1) corr += __shfl_xor(corr, sh, 64);

  if (lane == 0) {
    float* bk = bucket + (size_t)(row & (NBUCKET - 1)) * NQ;
    if (corr != 0.f) atomicAdd(bk + 0, -corr * il * (1.0f / (float)BB));
    if (tpk[0] != 0.f) atomicAdd(bk + 1, tpk[0]);
    if (tpk[1] != 0.f) atomicAdd(bk + 2, tpk[1]);
    if (tpk[2] != 0.f) atomicAdd(bk + 3, tpk[2]);
    if (tpk[3] != 0.f) atomicAdd(bk + 4, tpk[3]);
  }
}

// ---------------- phase 3: bucket reduce ----------------
__global__ __launch_bounds__(64) void reduce_kernel(const float* __restrict__ bucket,
                                                    float* __restrict__ out) {
  const int lane = threadIdx.x;
  float acc[NQ];
  #pragma unroll
  for (int q = 0; q < NQ; ++q) acc[q] = bucket[lane * NQ + q];
  #pragma unroll
  for (int q = 0; q < NQ; ++q) {
    #pragma unroll
    for (int s = 32; s >= 1; s >>= 1) acc[q] += __shfl_xor(acc[q], s, 64);
  }
  if (lane == 0) {
    #pragma unroll
    for (int q = 0; q < NQ; ++q) out[q] = acc[q];
  }
}

extern "C" void kernel_launch(void* const* d_in, const int* in_sizes, int n_in,
                              void* d_out, int out_size, void* d_ws, size_t ws_size,
                              hipStream_t stream) {
  const float* yhat = (const float*)d_in[0];
  const float* yy   = (const float*)d_in[1];
  const float* len  = (const float*)d_in[2];
  float* out = (float*)d_out;

  uint8_t* ws = (uint8_t*)d_ws;
  float*    bucket = (float*)ws;                        // 4 KB region
  uint32_t* cnt    = (uint32_t*)(ws + 4096);            // 32 KB
  uint32_t* ppos   = (uint32_t*)(ws + 36864);           // 32 KB
  uint32_t* cand   = (uint32_t*)(ws + 69632);           // 8192*64*4 = 2 MB
  uint16_t* pidx   = (uint16_t*)(ws + 2166784);         // 8192*96*2 = 1.5 MB
  // total ws usage: ~3.57 MB

  hipMemsetAsync(ws, 0, 69632, stream);                 // bucket + cnt + ppos
  stream_kernel<<<2048, 256, 0, stream>>>(yhat, yy, len, bucket, cnt, ppos, cand, pidx);
  rank_kernel<<<NROWS, 64, 0, stream>>>(yhat, yy, len, bucket, cnt, ppos, cand, pidx);
  reduce_kernel<<<1, 64, 0, stream>>>(bucket, out);
}

// Round 8
// 126.027 us; speedup vs baseline: 1.4634x; 1.4634x over previous
//
#include <hip/hip_runtime.h>
#include <stdint.h>

#define TT 64
#define BB 128
#define VV 4880
#define NF4R 1220                    // float4 per row
#define NROWS (TT * BB)              // 8192
#define LOG_EPS_F 1e-8f
#define NBUCKET 64
#define NQ 9
#define THR0 0.992f                  // ~38 candidate chunks/row (band 20..64)
#define FCAP 64                      // per-row candidate-chunk capacity
#define PCAP 96                      // per-row positive-chunk capacity (~47 avg)

// full u64 key (rescan path): (value desc, idx asc) via single compare
__device__ __forceinline__ uint64_t mkkey64(float v, int idx) {
  return ((uint64_t)__float_as_uint(v) << 13) | (uint64_t)(8191 - idx);
}
// compact u32 key, valid for v > THR0; same ordering as mkkey64 there
__device__ __forceinline__ uint32_t mkkey32(float v, uint32_t idx) {
  return ((__float_as_uint(v) - __float_as_uint(THR0)) << 13) | (8191u - idx);
}
__device__ __forceinline__ int lane_prefix(unsigned long long m) {
  return __builtin_amdgcn_mbcnt_hi((unsigned)(m >> 32),
         __builtin_amdgcn_mbcnt_lo((unsigned)m, 0));
}

// ---------------- phase 1: stream-split scan (each wave = ONE stream) -------
__global__ __launch_bounds__(256) void scan_kernel(
    const float* __restrict__ yhat, const float* __restrict__ yy,
    const float* __restrict__ length, float* __restrict__ bucket,
    uint32_t* __restrict__ fcnt, uint32_t* __restrict__ pcnt,
    uint16_t* __restrict__ fcand, uint16_t* __restrict__ pidx) {
  __shared__ uint16_t sbuf[4][PCAP];   // per-wave slice (H uses first 64)
  const int wid  = threadIdx.x >> 6;
  const int lane = threadIdx.x & 63;
  uint16_t* sb = sbuf[wid];

  if (blockIdx.x < 2048) {
    // ================= H-PASS: read y_hat row only =================
    const int row = blockIdx.x * 4 + wid;
    const float4* hr = (const float4*)(yhat + (size_t)row * VV);
    const float il = 1.0f / length[row & (BB - 1)];
    float logsum = 0.f;
    int cnt = 0;

    auto hproc = [&](float4 h, int f) {
      float a0 = (1.0f - h.x) + LOG_EPS_F, a1 = (1.0f - h.y) + LOG_EPS_F;
      float a2 = (1.0f - h.z) + LOG_EPS_F, a3 = (1.0f - h.w) + LOG_EPS_F;
      logsum += __logf((a0 * a1) * (a2 * a3));     // product >= ~1e-16
      int mk = (h.x > THR0 ? 1 : 0) | (h.y > THR0 ? 2 : 0) |
               (h.z > THR0 ? 4 : 0) | (h.w > THR0 ? 8 : 0);
      unsigned long long bal = __ballot(mk != 0);
      if (bal) {
        if (mk) { int s = cnt + lane_prefix(bal);
                  if (s < FCAP) sb[s] = (uint16_t)((mk << 11) | f); }
        cnt += __popcll(bal);
      }
    };

    float4 a0v, a1v, a2v, a3v, b0v, b1v, b2v, b3v;
#define HLD(Q0,Q1,Q2,Q3,c0) Q0=hr[lane+64*(c0)]; Q1=hr[lane+64*((c0)+1)]; \
                            Q2=hr[lane+64*((c0)+2)]; Q3=hr[lane+64*((c0)+3)];
#define HPR(Q0,Q1,Q2,Q3,c0) hproc(Q0,lane+64*(c0)); hproc(Q1,lane+64*((c0)+1)); \
                            hproc(Q2,lane+64*((c0)+2)); hproc(Q3,lane+64*((c0)+3));
    HLD(a0v,a1v,a2v,a3v, 0)
    HLD(b0v,b1v,b2v,b3v, 4)
    HPR(a0v,a1v,a2v,a3v, 0)
    HLD(a0v,a1v,a2v,a3v, 8)
    HPR(b0v,b1v,b2v,b3v, 4)
    HLD(b0v,b1v,b2v,b3v, 12)
    HPR(a0v,a1v,a2v,a3v, 8)
    a0v = hr[lane + 1024]; a1v = hr[lane + 1088]; a2v = hr[lane + 1152];
    { bool act = lane < 4;
      a3v = hr[act ? (1216 + lane) : 0];
      if (!act) a3v = make_float4(0.f, 0.f, 0.f, 0.f); }
    HPR(b0v,b1v,b2v,b3v, 12)
    hproc(a0v, lane + 1024); hproc(a1v, lane + 1088);
    hproc(a2v, lane + 1152); hproc(a3v, 1216 + lane);
#undef HLD
#undef HPR

    const int fcp = (cnt < FCAP) ? cnt : FCAP;
    if (lane < fcp) fcand[row * FCAP + lane] = sb[lane];
    if (lane == 0) fcnt[row] = (uint32_t)cnt;
    #pragma unroll
    for (int sh = 32; sh >= 1; sh >>= 1) logsum += __shfl_xor(logsum, sh, 64);
    if (lane == 0) {
      float* bk = bucket + (size_t)(row & (NBUCKET - 1)) * NQ;
      atomicAdd(bk + 0, -logsum * il * (1.0f / (float)BB));
    }
  } else {
    // ================= Y-PASS: read y row only =================
    const int row = (blockIdx.x - 2048) * 4 + wid;
    const float4* yr = (const float4*)(yy + (size_t)row * VV);
    float np = 0.f;
    int cnt = 0;

    auto yproc = [&](float4 v, int f) {
      np += (v.x + v.y) + (v.z + v.w);             // y is exactly 0/1
      int mk = (v.x != 0.f ? 1 : 0) | (v.y != 0.f ? 2 : 0) |
               (v.z != 0.f ? 4 : 0) | (v.w != 0.f ? 8 : 0);
      unsigned long long bal = __ballot(mk != 0);
      if (bal) {
        if (mk) { int s = cnt + lane_prefix(bal);
                  if (s < PCAP) sb[s] = (uint16_t)((mk << 11) | f); }
        cnt += __popcll(bal);
      }
    };

    float4 a0v, a1v, a2v, a3v, b0v, b1v, b2v, b3v;
#define YLD(Q0,Q1,Q2,Q3,c0) Q0=yr[lane+64*(c0)]; Q1=yr[lane+64*((c0)+1)]; \
                            Q2=yr[lane+64*((c0)+2)]; Q3=yr[lane+64*((c0)+3)];
#define YPR(Q0,Q1,Q2,Q3,c0) yproc(Q0,lane+64*(c0)); yproc(Q1,lane+64*((c0)+1)); \
                            yproc(Q2,lane+64*((c0)+2)); yproc(Q3,lane+64*((c0)+3));
    YLD(a0v,a1v,a2v,a3v, 0)
    YLD(b0v,b1v,b2v,b3v, 4)
    YPR(a0v,a1v,a2v,a3v, 0)
    YLD(a0v,a1v,a2v,a3v, 8)
    YPR(b0v,b1v,b2v,b3v, 4)
    YLD(b0v,b1v,b2v,b3v, 12)
    YPR(a0v,a1v,a2v,a3v, 8)
    a0v = yr[lane + 1024]; a1v = yr[lane + 1088]; a2v = yr[lane + 1152];
    { bool act = lane < 4;
      a3v = yr[act ? (1216 + lane) : 0];
      if (!act) a3v = make_float4(0.f, 0.f, 0.f, 0.f); }
    YPR(b0v,b1v,b2v,b3v, 12)
    yproc(a0v, lane + 1024); yproc(a1v, lane + 1088);
    yproc(a2v, lane + 1152); yproc(a3v, 1216 + lane);
#undef YLD
#undef YPR

    const int pcp = (cnt < PCAP) ? cnt : PCAP;
    if (lane < pcp) pidx[row * PCAP + lane] = sb[lane];
    if (lane + 64 < pcp) pidx[row * PCAP + lane + 64] = sb[lane + 64];
    if (lane == 0) pcnt[row] = (uint32_t)cnt;
    #pragma unroll
    for (int sh = 32; sh >= 1; sh >>= 1) np += __shfl_xor(np, sh, 64);
    if (lane == 0) {
      float* bk = bucket + (size_t)(row & (NBUCKET - 1)) * NQ;
      atomicAdd(bk + 5, np); atomicAdd(bk + 6, np);
      atomicAdd(bk + 7, np); atomicAdd(bk + 8, np);
    }
  }
}

// ---------------- phase 2: per-row merge + ranking ----------------
__global__ __launch_bounds__(64) void rank_kernel(
    const float* __restrict__ yhat, const float* __restrict__ yy,
    const float* __restrict__ length, float* __restrict__ bucket,
    const uint32_t* __restrict__ fcnt, const uint32_t* __restrict__ pcnt,
    const uint16_t* __restrict__ fcand, const uint16_t* __restrict__ pidx) {
  __shared__ int fbuf[64];
  const int row  = blockIdx.x;
  const int lane = threadIdx.x;
  const uint32_t fc = fcnt[row];
  const uint32_t pc = pcnt[row];
  const float il = 1.0f / length[row & (BB - 1)];
  const float4* hr = (const float4*)(yhat + (size_t)row * VV);

  float corr = 0.f;                  // sum over positives: log(yh+e)-log(1-yh+e)
  float tpk[4] = {0.f, 0.f, 0.f, 0.f};

  if (fc >= 20 && fc <= FCAP && pc <= PCAP) {
    uint32_t ent = (lane < (int)fc) ? fcand[row * FCAP + lane] : 0u;
    int f  = ent & 0x7FF;
    int am = (int)(ent >> 11);
    float4 h = hr[f];
    uint32_t k0 = (am & 1) ? mkkey32(h.x, 4 * f)     : 0u;
    uint32_t k1 = (am & 2) ? mkkey32(h.y, 4 * f + 1) : 0u;
    uint32_t k2 = (am & 4) ? mkkey32(h.z, 4 * f + 2) : 0u;
    uint32_t k3 = (am & 8) ? mkkey32(h.w, 4 * f + 3) : 0u;

    #pragma unroll
    for (int batch = 0; batch < 2; ++batch) {
      int p = lane + 64 * batch;
      uint32_t pe = (p < (int)pc) ? pidx[row * PCAP + p] : 0u;
      int fp = pe & 0x7FF;
      int pm = (p < (int)pc) ? (int)(pe >> 11) : 0;
      float4 hp = hr[fp];
      if (pm & 1) corr += __logf(hp.x + LOG_EPS_F) - __logf(1.f - hp.x + LOG_EPS_F);
      if (pm & 2) corr += __logf(hp.y + LOG_EPS_F) - __logf(1.f - hp.y + LOG_EPS_F);
      if (pm & 4) corr += __logf(hp.z + LOG_EPS_F) - __logf(1.f - hp.z + LOG_EPS_F);
      if (pm & 8) corr += __logf(hp.w + LOG_EPS_F) - __logf(1.f - hp.w + LOG_EPS_F);
      int hm = ((pm & 1) && hp.x > THR0 ? 1 : 0) | ((pm & 2) && hp.y > THR0 ? 2 : 0) |
               ((pm & 4) && hp.z > THR0 ? 4 : 0) | ((pm & 8) && hp.w > THR0 ? 8 : 0);
      unsigned long long bal = __ballot(hm != 0);
      while (bal) {                                  // ~0.4 positives>thr per row
        int s = __builtin_ctzll(bal);
        bal &= bal - 1;
        int flags = __shfl(hm, s, 64);
        int bf    = __shfl(fp, s, 64);
        float bx = __shfl(hp.x, s, 64), by = __shfl(hp.y, s, 64);
        float bz = __shfl(hp.z, s, 64), bw = __shfl(hp.w, s, 64);
        #pragma unroll
        for (int e = 0; e < 4; ++e) {
          if (flags & (1 << e)) {                    // wave-uniform
            float bv = (e == 0) ? bx : (e == 1) ? by : (e == 2) ? bz : bw;
            uint32_t pk = mkkey32(bv, (uint32_t)(4 * bf + e));
            int cc = ((k0 > pk) ? 1 : 0) + ((k1 > pk) ? 1 : 0) +
                     ((k2 > pk) ? 1 : 0) + ((k3 > pk) ? 1 : 0);
            #pragma unroll
            for (int sh = 32; sh >= 1; sh >>= 1) cc += __shfl_xor(cc, sh, 64);
            tpk[0] += (cc < 5);  tpk[1] += (cc < 10);
            tpk[2] += (cc < 15); tpk[3] += (cc < 20);
          }
        }
      }
    }
  } else {
    // ---- rescan path (rare; handles band misses exactly) ----
    const float4* yr = (const float4*)(yy + (size_t)row * VV);
    float thr = THR0;
    auto scan = [&](float th) {
      int c2 = 0;
      for (int f = lane; f < NF4R; f += 64) {
        float4 h = hr[f];
        float hmv = fmaxf(fmaxf(h.x, h.y), fmaxf(h.z, h.w));
        bool take = hmv > th;
        unsigned long long m = __ballot(take);
        if (m) {
          if (take) { int s = c2 + lane_prefix(m); if (s < 64) fbuf[s] = f; }
          c2 += __popcll(m);
        }
      }
      return c2;
    };
    int lc = scan(thr);
    int attempt = 0;
    while ((lc < 20 || lc > 64) && attempt < 10) {
      thr = (lc < 20) ? 1.0f - (1.0f - thr) * 2.5f
                      : 1.0f - (1.0f - thr) * 0.4f;
      lc = scan(thr);
      ++attempt;
    }
    const int tl = (lc < 64) ? lc : 64;
    const bool act = (lane < tl);
    const int f = act ? fbuf[lane] : 0;
    float4 h = hr[f], v = yr[f];
    uint64_t K0 = mkkey64(h.x, 4 * f),     K1 = mkkey64(h.y, 4 * f + 1);
    uint64_t K2 = mkkey64(h.z, 4 * f + 2), K3 = mkkey64(h.w, 4 * f + 3);
    const bool ve0 = act && (h.x > thr), ve1 = act && (h.y > thr);
    const bool ve2 = act && (h.z > thr), ve3 = act && (h.w > thr);
    int pmask = (ve0 && v.x != 0.0f) ? 1 : 0;
    pmask |= (ve1 && v.y != 0.0f) ? 2 : 0;
    pmask |= (ve2 && v.z != 0.0f) ? 4 : 0;
    pmask |= (ve3 && v.w != 0.0f) ? 8 : 0;
    unsigned long long pl = __ballot(pmask != 0);
    while (pl) {
      int s = __builtin_ctzll(pl);
      pl &= pl - 1;
      int flags = __shfl(pmask, s, 64);
      uint64_t pk0 = __shfl((unsigned long long)K0, s, 64);
      uint64_t pk1 = __shfl((unsigned long long)K1, s, 64);
      uint64_t pk2 = __shfl((unsigned long long)K2, s, 64);
      uint64_t pk3 = __shfl((unsigned long long)K3, s, 64);
      #pragma unroll
      for (int e = 0; e < 4; ++e) {
        if (flags & (1 << e)) {
          uint64_t pk = (e == 0) ? pk0 : (e == 1) ? pk1 : (e == 2) ? pk2 : pk3;
          int cc = (ve0 && K0 > pk) + (ve1 && K1 > pk) +
                   (ve2 && K2 > pk) + (ve3 && K3 > pk);
          #pragma unroll
          for (int sh = 32; sh >= 1; sh >>= 1) cc += __shfl_xor(cc, sh, 64);
          tpk[0] += (cc < 5);  tpk[1] += (cc < 10);
          tpk[2] += (cc < 15); tpk[3] += (cc < 20);
        }
      }
    }
    for (int ff = lane; ff < NF4R; ff += 64) {       // corr over ALL positives
      float4 vv = yr[ff];
      if (vv.x != 0.f || vv.y != 0.f || vv.z != 0.f || vv.w != 0.f) {
        float4 hh = hr[ff];
        if (vv.x != 0.f) corr += __logf(hh.x + LOG_EPS_F) - __logf(1.f - hh.x + LOG_EPS_F);
        if (vv.y != 0.f) corr += __logf(hh.y + LOG_EPS_F) - __logf(1.f - hh.y + LOG_EPS_F);
        if (vv.z != 0.f) corr += __logf(hh.z + LOG_EPS_F) - __logf(1.f - hh.z + LOG_EPS_F);
        if (vv.w != 0.f) corr += __logf(hh.w + LOG_EPS_F) - __logf(1.f - hh.w + LOG_EPS_F);
      }
    }
  }

  #pragma unroll
  for (int sh = 32; sh >= 1; sh >>= 1) corr += __shfl_xor(corr, sh, 64);

  if (lane == 0) {
    float* bk = bucket + (size_t)(row & (NBUCKET - 1)) * NQ;
    if (corr != 0.f) atomicAdd(bk + 0, -corr * il * (1.0f / (float)BB));
    if (tpk[0] != 0.f) atomicAdd(bk + 1, tpk[0]);
    if (tpk[1] != 0.f) atomicAdd(bk + 2, tpk[1]);
    if (tpk[2] != 0.f) atomicAdd(bk + 3, tpk[2]);
    if (tpk[3] != 0.f) atomicAdd(bk + 4, tpk[3]);
  }
}

// ---------------- phase 3: bucket reduce ----------------
__global__ __launch_bounds__(64) void reduce_kernel(const float* __restrict__ bucket,
                                                    float* __restrict__ out) {
  const int lane = threadIdx.x;
  float acc[NQ];
  #pragma unroll
  for (int q = 0; q < NQ; ++q) acc[q] = bucket[lane * NQ + q];
  #pragma unroll
  for (int q = 0; q < NQ; ++q) {
    #pragma unroll
    for (int s = 32; s >= 1; s >>= 1) acc[q] += __shfl_xor(acc[q], s, 64);
  }
  if (lane == 0) {
    #pragma unroll
    for (int q = 0; q < NQ; ++q) out[q] = acc[q];
  }
}

extern "C" void kernel_launch(void* const* d_in, const int* in_sizes, int n_in,
                              void* d_out, int out_size, void* d_ws, size_t ws_size,
                              hipStream_t stream) {
  const float* yhat = (const float*)d_in[0];
  const float* yy   = (const float*)d_in[1];
  const float* len  = (const float*)d_in[2];
  float* out = (float*)d_out;

  uint8_t* ws = (uint8_t*)d_ws;
  float*    bucket = (float*)ws;                       // 2304 B (pad to 4K)
  uint32_t* fcnt   = (uint32_t*)(ws + 4096);           // 32 KB
  uint32_t* pcnt   = (uint32_t*)(ws + 36864);          // 32 KB
  uint16_t* fcand  = (uint16_t*)(ws + 69632);          // 8192*64*2 = 1 MB
  uint16_t* pidx   = (uint16_t*)(ws + 1118208);        // 8192*96*2 = 1.5 MB
  // total ws usage ~2.57 MB

  hipMemsetAsync(ws, 0, 69632, stream);                // bucket + fcnt + pcnt
  scan_kernel<<<4096, 256, 0, stream>>>(yhat, yy, len, bucket, fcnt, pcnt, fcand, pidx);
  rank_kernel<<<NROWS, 64, 0, stream>>>(yhat, yy, len, bucket, fcnt, pcnt, fcand, pidx);
  reduce_kernel<<<1, 64, 0, stream>>>(bucket, out);
}

// Round 9
// 103.747 us; speedup vs baseline: 1.7777x; 1.2148x over previous
//
#include <hip/hip_runtime.h>
#include <stdint.h>

#define TT 64
#define BB 128
#define VV 4880
#define NF4 (VV / 4)          // 1220 float4 per row
#define NROWS (TT * BB)       // 8192
#define LOG_EPS_F 1e-8f
#define CAP 256               // max stored candidates per row
#define PCAP 64               // max stored positive candidates per row
#define NBUCKET 64
#define NQ 9
#define THR0 0.98f

// Pack (value, row-local idx) so that u64 max-compare == (value desc, idx asc).
__device__ __forceinline__ uint64_t mkkey(float v, int idx) {
  return ((uint64_t)__float_as_uint(v) << 13) | (uint64_t)(8191 - idx);
}

__device__ __forceinline__ int lane_prefix(unsigned long long m) {
  return __builtin_amdgcn_mbcnt_hi((unsigned)(m >> 32),
         __builtin_amdgcn_mbcnt_lo((unsigned)m, 0));
}

__global__ __launch_bounds__(256) void pass_kernel(
    const float* __restrict__ yhat, const float* __restrict__ yy,
    const float* __restrict__ length, float* __restrict__ bucket) {
  __shared__ uint64_t cand[4][CAP];
  __shared__ uint64_t pcand[4][PCAP];

  const int wid  = threadIdx.x >> 6;    // wave 0..3
  const int lane = threadIdx.x & 63;
  const int row  = blockIdx.x * 4 + wid;   // row = t*B + b
  const int b    = row & (BB - 1);
  const float4* h4 = (const float4*)(yhat + (size_t)row * VV);
  const float4* y4 = (const float4*)(yy   + (size_t)row * VV);
  uint64_t* cd = cand[wid];             // this wave's private slices
  uint64_t* pc = pcand[wid];

  float logsum = 0.0f;   // sum of log(selected); ce = -logsum
  float nposf  = 0.0f;
  float thr    = THR0;
  int   cnt    = 0;      // wave-uniform candidate count
  int   pcnt   = 0;      // wave-uniform positive-candidate count

  // ballot-compaction insert: no LDS atomics, no round-trip dependency
  auto slot = [&](float v, float yv, int idx) {
    bool take = v > thr;
    unsigned long long m = __ballot(take);
    if (m) {
      if (take) {
        int s = cnt + lane_prefix(m);
        if (s < CAP) cd[s] = mkkey(v, idx);
      }
      cnt += __popcll(m);
      bool pt = take && (yv != 0.0f);
      unsigned long long pm = __ballot(pt);
      if (pm) {
        if (pt) {
          int sp = pcnt + lane_prefix(pm);
          if (sp < PCAP) pc[sp] = mkkey(v, idx);
        }
        pcnt += __popcll(pm);
      }
    }
  };
  // full processing of one float4 pair (BCE via product-of-4 + candidates)
  auto procf4 = [&](float4 h, float4 v, int base) {
    float a0 = ((v.x != 0.0f) ? h.x : (1.0f - h.x)) + LOG_EPS_F;
    float a1 = ((v.y != 0.0f) ? h.y : (1.0f - h.y)) + LOG_EPS_F;
    float a2 = ((v.z != 0.0f) ? h.z : (1.0f - h.z)) + LOG_EPS_F;
    float a3 = ((v.w != 0.0f) ? h.w : (1.0f - h.w)) + LOG_EPS_F;
    logsum += __logf((a0 * a1) * (a2 * a3));   // product >= 1e-16, no underflow
    nposf  += (v.x + v.y) + (v.z + v.w);       // y is exactly 0.0/1.0
    slot(h.x, v.x, base);     slot(h.y, v.y, base + 1);
    slot(h.z, v.z, base + 2); slot(h.w, v.w, base + 3);
  };

  // ---- main scan: 20 chunks, 3-deep rotating 2-chunk batches ----
  // Batch k covers chunks (2k, 2k+1); 3 batches (12 KB) in flight continuously.
  float4 h0a, h0b, v0a, v0b;   // batch slot 0
  float4 h1a, h1b, v1a, v1b;   // batch slot 1
  float4 h2a, h2b, v2a, v2b;   // batch slot 2

#define LDB(HA,VA,HB,VB,cA,cB) \
  HA = h4[lane + 64 * (cA)]; VA = y4[lane + 64 * (cA)]; \
  HB = h4[lane + 64 * (cB)]; VB = y4[lane + 64 * (cB)];
#define PRB(HA,VA,HB,VB,cA,cB) \
  procf4(HA, VA, 4 * (lane + 64 * (cA))); \
  procf4(HB, VB, 4 * (lane + 64 * (cB)));

  // prologue: 3 batches issued (12 loads outstanding)
  LDB(h0a,v0a,h0b,v0b, 0,1)
  LDB(h1a,v1a,h1b,v1b, 2,3)
  LDB(h2a,v2a,h2b,v2b, 4,5)
  // steady state: process batch k, immediately issue batch k+3
  PRB(h0a,v0a,h0b,v0b, 0,1)   LDB(h0a,v0a,h0b,v0b, 6,7)
  PRB(h1a,v1a,h1b,v1b, 2,3)   LDB(h1a,v1a,h1b,v1b, 8,9)
  PRB(h2a,v2a,h2b,v2b, 4,5)   LDB(h2a,v2a,h2b,v2b, 10,11)
  PRB(h0a,v0a,h0b,v0b, 6,7)   LDB(h0a,v0a,h0b,v0b, 12,13)
  PRB(h1a,v1a,h1b,v1b, 8,9)   LDB(h1a,v1a,h1b,v1b, 14,15)
  PRB(h2a,v2a,h2b,v2b, 10,11) LDB(h2a,v2a,h2b,v2b, 16,17)
  PRB(h0a,v0a,h0b,v0b, 12,13)
  {  // batch 9: chunk 18 full, chunk 19 predicated (lanes 0-3 only)
    h0a = h4[lane + 64 * 18]; v0a = y4[lane + 64 * 18];
    const bool act = (lane < 4);
    const int f_ = act ? (1216 + lane) : 1216;
    h0b = h4[f_]; v0b = y4[f_];
    if (!act) { h0b = make_float4(0, 0, 0, 0); v0b = make_float4(0, 0, 0, 0); }
  }
  PRB(h1a,v1a,h1b,v1b, 14,15)
  PRB(h2a,v2a,h2b,v2b, 16,17)
  PRB(h0a,v0a,h0b,v0b, 18,19)  // inactive lanes: a=1.0 exactly -> log 0, no take
#undef LDB
#undef PRB

  // ---- per-wave retry (wave-uniform; never taken on this data) ----
  int attempt = 0;
  while (!(cnt >= 20 && cnt <= CAP) && attempt < 6) {
    thr = (cnt < 20) ? 1.0f - (1.0f - thr) * 4.0f
                     : 1.0f - (1.0f - thr) * 0.25f;
    cnt = 0; pcnt = 0;
    for (int f = lane; f < NF4; f += 64) {
      float4 h = h4[f], v = y4[f];
      slot(h.x, v.x, 4 * f);     slot(h.y, v.y, 4 * f + 1);
      slot(h.z, v.z, 4 * f + 2); slot(h.w, v.w, 4 * f + 3);
    }
    ++attempt;
  }
  if (cnt > CAP)   cnt  = CAP;
  if (pcnt > PCAP) pcnt = PCAP;

  // ---- rank each positive candidate: rank = #{cand keys > key(p)} ----
  float tpk[4] = {0.f, 0.f, 0.f, 0.f};
  for (int p = 0; p < pcnt; ++p) {
    uint64_t pk = pc[p];
    int c = 0;
    for (int j = lane; j < cnt; j += 64) c += (cd[j] > pk) ? 1 : 0;
    #pragma unroll
    for (int s = 32; s >= 1; s >>= 1) c += __shfl_xor(c, s, 64);
    tpk[0] += (c < 5);  tpk[1] += (c < 10);
    tpk[2] += (c < 15); tpk[3] += (c < 20);
  }

  // ---- wave reductions for ce and n_pos ----
  #pragma unroll
  for (int s = 32; s >= 1; s >>= 1) {
    logsum += __shfl_xor(logsum, s, 64);
    nposf  += __shfl_xor(nposf, s, 64);
  }

  if (lane == 0) {
    float* bk = bucket + (size_t)(row & (NBUCKET - 1)) * NQ;
    float ce = -logsum / (length[b] * (float)BB);
    atomicAdd(bk + 0, ce);
    atomicAdd(bk + 1, tpk[0]);
    atomicAdd(bk + 2, tpk[1]);
    atomicAdd(bk + 3, tpk[2]);
    atomicAdd(bk + 4, tpk[3]);
    atomicAdd(bk + 5, nposf);
    atomicAdd(bk + 6, nposf);
    atomicAdd(bk + 7, nposf);
    atomicAdd(bk + 8, nposf);
  }
}

__global__ __launch_bounds__(64) void reduce_kernel(const float* __restrict__ bucket,
                                                    float* __restrict__ out) {
  const int lane = threadIdx.x;  // 64 lanes, one bucket each
  float acc[NQ];
  #pragma unroll
  for (int q = 0; q < NQ; ++q) acc[q] = bucket[lane * NQ + q];
  #pragma unroll
  for (int q = 0; q < NQ; ++q) {
    #pragma unroll
    for (int s = 32; s >= 1; s >>= 1) acc[q] += __shfl_xor(acc[q], s, 64);
  }
  if (lane == 0) {
    #pragma unroll
    for (int q = 0; q < NQ; ++q) out[q] = acc[q];
  }
}

extern "C" void kernel_launch(void* const* d_in, const int* in_sizes, int n_in,
                              void* d_out, int out_size, void* d_ws, size_t ws_size,
                              hipStream_t stream) {
  const float* yhat = (const float*)d_in[0];
  const float* yy   = (const float*)d_in[1];
  const float* len  = (const float*)d_in[2];
  float* out    = (float*)d_out;
  float* bucket = (float*)d_ws;   // NBUCKET*NQ floats = 2304 B

  hipMemsetAsync(bucket, 0, NBUCKET * NQ * sizeof(float), stream);
  pass_kernel<<<NROWS / 4, 256, 0, stream>>>(yhat, yy, len, bucket);
  reduce_kernel<<<1, 64, 0, stream>>>(bucket, out);
}